// Round 6
// baseline (464.097 us; speedup 1.0000x reference)
//
#include <hip/hip_runtime.h>

#define N_NODES 100000
#define N_EDGES 500000
#define D 256
#define CAP 32          // bucket capacity per (node, relation); λ=5 ⇒ P(deg>32)≈1e-15

typedef __bf16 bf16x8 __attribute__((ext_vector_type(8)));
typedef float  f32x4  __attribute__((ext_vector_type(4)));
typedef unsigned int u32x2 __attribute__((ext_vector_type(2)));  // nontemporal-compatible

// async global->LDS, 16B per lane; LDS dest must be wave-uniform base + lane*16
#define GLDS(gp, lp) \
    __builtin_amdgcn_global_load_lds((const __attribute__((address_space(1))) void*)(gp), \
                                     (__attribute__((address_space(3))) void*)(lp), 16, 0, 0)

// ---- bf16 helpers (manual, RNE) -------------------------------------------
__device__ __forceinline__ unsigned short f2bf(float f) {
    unsigned int u = __float_as_uint(f);
    u += 0x7fffu + ((u >> 16) & 1u);
    return (unsigned short)(u >> 16);
}
__device__ __forceinline__ float bf2f(unsigned short b) {
    return __uint_as_float(((unsigned int)b) << 16);
}

// ---------------------------------------------------------------------------
// Fused prep kernel. Role order matters: bucket blocks FIRST so the
// latency-bound edge scatter fills the machine and runs CONCURRENTLY with
// the bandwidth-bound convert stream that dispatches behind it (round-4
// showed segregated-order roles serialize: 131 µs at 1.3 TB/s).
//   blocks [0, 977)          : bucket edges by dst, 4 edges/thread (int4 MLP)
//   blocks [977, 1745)       : Wt[n][k] = bf16(scale_k * W[k%256][n]), 1.1 folded
//   blocks [1745, 14245)     : x fp32 -> bf16 (8 elems/thread, coalesced)
// ---------------------------------------------------------------------------
#define BKT_B    977
#define PW_B     768
#define CONV_B   12500
#define PREP_GRID (BKT_B + PW_B + CONV_B)

__global__ __launch_bounds__(256) void prep_kernel(
    const float* __restrict__ x, unsigned short* __restrict__ xb,
    const float* __restrict__ Ws, const float* __restrict__ W1,
    const float* __restrict__ W2, unsigned short* __restrict__ Wt,
    const int* __restrict__ src1, const int* __restrict__ dst1,
    const int* __restrict__ src2, const int* __restrict__ dst2,
    int* __restrict__ cnt1, int* __restrict__ cnt2,
    int* __restrict__ bkt1, int* __restrict__ bkt2)
{
    const int b = blockIdx.x;
    const int tid = threadIdx.x;
    if (b < BKT_B) {
        // quad-of-edges index; 2*500000/4 = 250000 quads. 500000%4==0 so a
        // quad never straddles the relation boundary.
        int q = b * 256 + tid;
        if (q >= 250000) return;
        const int* src; const int* dst; int* cnt; int* bkt; int qi;
        if (q < 125000) { src = src1; dst = dst1; cnt = cnt1; bkt = bkt1; qi = q; }
        else            { src = src2; dst = dst2; cnt = cnt2; bkt = bkt2; qi = q - 125000; }
        int4 s = ((const int4*)src)[qi];
        int4 d = ((const int4*)dst)[qi];
        int p0 = atomicAdd(&cnt[d.x], 1); if (p0 < CAP) bkt[d.x * CAP + p0] = s.x;
        int p1 = atomicAdd(&cnt[d.y], 1); if (p1 < CAP) bkt[d.y * CAP + p1] = s.y;
        int p2 = atomicAdd(&cnt[d.z], 1); if (p2 < CAP) bkt[d.z * CAP + p2] = s.z;
        int p3 = atomicAdd(&cnt[d.w], 1); if (p3 < CAP) bkt[d.w * CAP + p3] = s.w;
    } else if (b < BKT_B + PW_B) {
        int idx = (b - BKT_B) * 256 + tid;       // over 768*256, reads coalesced in n
        int k = idx >> 8;
        int n = idx & (D - 1);
        const float* W = (k < D) ? Ws : (k < 2 * D ? W1 : W2);
        float scale = (k < D) ? 1.1f : 1.0f;
        Wt[(size_t)n * (3 * D) + k] = f2bf(W[(size_t)(k & (D - 1)) * D + n] * scale);
    } else {
        size_t i = ((size_t)(b - BKT_B - PW_B) * 256 + tid) * 8;
        if (i >= (size_t)N_NODES * D) return;
        float4 a = *(const float4*)(x + i);
        float4 c = *(const float4*)(x + i + 4);
        union { unsigned short s[8]; uint4 u; } o;
        o.s[0] = f2bf(a.x); o.s[1] = f2bf(a.y); o.s[2] = f2bf(a.z); o.s[3] = f2bf(a.w);
        o.s[4] = f2bf(c.x); o.s[5] = f2bf(c.y); o.s[6] = f2bf(c.z); o.s[7] = f2bf(c.w);
        *(uint4*)(xb + i) = o.u;   // normal store: primes L3 with xb for gather
    }
}

// ---------------------------------------------------------------------------
// Gather: one wave per node, BOTH relations (16 independent 512B row-loads in
// flight -> MLP). xa writes are NON-TEMPORAL: round-3 FETCH=250MB vs 77MB
// compulsory showed the xa write-allocate stream was evicting xb from L3.
// ---------------------------------------------------------------------------
__global__ __launch_bounds__(256) void gather_kernel(
    const unsigned short* __restrict__ xb,
    const int* __restrict__ cnt1, const int* __restrict__ cnt2,
    const int* __restrict__ bkt1, const int* __restrict__ bkt2,
    unsigned short* __restrict__ xa1, unsigned short* __restrict__ xa2)
{
    long long gid = (long long)blockIdx.x * blockDim.x + threadIdx.x;
    int node = (int)(gid >> 6);
    int lane = (int)(gid & 63);
    if (node >= N_NODES) return;

    int c1 = cnt1[node]; if (c1 > CAP) c1 = CAP;
    int c2 = cnt2[node]; if (c2 > CAP) c2 = CAP;

    int sid1 = (lane < c1) ? bkt1[(size_t)node * CAP + lane] : 0;
    int sid2 = (lane < c2) ? bkt2[(size_t)node * CAP + lane] : 0;

    // Issue 16 independent loads (8 per relation), accumulate predicated.
    // Dummy lanes load row 0 -> L1-hot broadcast, effectively free.
    ushort4 v1[8], v2[8];
    #pragma unroll
    for (int t = 0; t < 8; ++t) {
        int s = __shfl(sid1, t);
        v1[t] = *(const ushort4*)(xb + (size_t)s * D + lane * 4);
    }
    #pragma unroll
    for (int t = 0; t < 8; ++t) {
        int s = __shfl(sid2, t);
        v2[t] = *(const ushort4*)(xb + (size_t)s * D + lane * 4);
    }

    float a10 = 0.f, a11 = 0.f, a12 = 0.f, a13 = 0.f;
    float a20 = 0.f, a21 = 0.f, a22 = 0.f, a23 = 0.f;
    #pragma unroll
    for (int t = 0; t < 8; ++t) {
        if (t < c1) {   // wave-uniform predicate (scalar branch)
            a10 += bf2f(v1[t].x); a11 += bf2f(v1[t].y);
            a12 += bf2f(v1[t].z); a13 += bf2f(v1[t].w);
        }
        if (t < c2) {
            a20 += bf2f(v2[t].x); a21 += bf2f(v2[t].y);
            a22 += bf2f(v2[t].z); a23 += bf2f(v2[t].w);
        }
    }
    // Rare tails (P(c>8) ≈ 6.8% per relation at λ=5).
    for (int e = 8; e < c1; ++e) {
        int s = __shfl(sid1, e);
        ushort4 v = *(const ushort4*)(xb + (size_t)s * D + lane * 4);
        a10 += bf2f(v.x); a11 += bf2f(v.y); a12 += bf2f(v.z); a13 += bf2f(v.w);
    }
    for (int e = 8; e < c2; ++e) {
        int s = __shfl(sid2, e);
        ushort4 v = *(const ushort4*)(xb + (size_t)s * D + lane * 4);
        a20 += bf2f(v.x); a21 += bf2f(v.y); a22 += bf2f(v.z); a23 += bf2f(v.w);
    }

    u32x2 o1, o2;
    o1.x = (unsigned)f2bf(a10) | ((unsigned)f2bf(a11) << 16);
    o1.y = (unsigned)f2bf(a12) | ((unsigned)f2bf(a13) << 16);
    o2.x = (unsigned)f2bf(a20) | ((unsigned)f2bf(a21) << 16);
    o2.y = (unsigned)f2bf(a22) | ((unsigned)f2bf(a23) << 16);
    __builtin_nontemporal_store(o1, (u32x2*)(xa1 + (size_t)node * D + lane * 4));
    __builtin_nontemporal_store(o2, (u32x2*)(xa2 + (size_t)node * D + lane * 4));
}

// ---------------------------------------------------------------------------
// MFMA GEMM: out = relu( [xb | xa1 | xa2] @ Wt^T + bias ), bf16 in, fp32 acc.
// M=100000, N=256 (full N per block -> A read once), K=768.
// 512 threads = 8 waves, each 64x64 (4x4 of 16x16x32 MFMA). BK=32.
// Epilogue stores non-temporal (out never re-read; keep L3 for the A-stream).
// ---------------------------------------------------------------------------
__global__ __launch_bounds__(512) void gemm_kernel(
    const unsigned short* __restrict__ xb,
    const unsigned short* __restrict__ xa1,
    const unsigned short* __restrict__ xa2,
    const unsigned short* __restrict__ Wt,   // [256 n][768 k] bf16, pre-scaled
    const float* __restrict__ bias, float* __restrict__ out)
{
    __shared__ unsigned short Alds[128 * 32];   // [row][k] k-contiguous, 8 KB
    __shared__ unsigned short Blds[256 * 32];   // [n][k]  k-contiguous, 16 KB

    const int tid  = threadIdx.x;
    const int lane = tid & 63;
    const int wave = tid >> 6;          // 0..7
    const int quad = lane >> 4;
    const int l15  = lane & 15;
    const int m0 = blockIdx.x * 128;
    const int wm = (wave >> 2) * 64;    // 2 m-tiles x 4 n-tiles of 64
    const int wn = (wave & 3) * 64;

    const unsigned short* Aseg[3] = {xb, xa1, xa2};

    f32x4 acc[4][4] = {};

    for (int kt = 0; kt < 24; ++kt) {
        const int seg = kt >> 3;
        const int ko  = (kt & 7) * 32;
        const unsigned short* __restrict__ A = Aseg[seg];

        // A tile: 512 slots of 16B, 1/thread.
        {
            int row = tid >> 2, kq = tid & 3;
            int m = m0 + row;
            if (m >= N_NODES) m = N_NODES - 1;   // junk rows discarded in epilogue
            GLDS(A + (size_t)m * D + ko + kq * 8, Alds + tid * 8);
        }
        // B tile: 1024 slots of 16B, 2/thread (Wt rows are L2-resident).
        {
            int n = tid >> 2, kq = tid & 3;
            GLDS(Wt + (size_t)n * (3 * D) + kt * 32 + kq * 8, Blds + tid * 8);
        }
        {
            int t2 = tid + 512;
            int n = t2 >> 2, kq = t2 & 3;
            GLDS(Wt + (size_t)n * (3 * D) + kt * 32 + kq * 8, Blds + t2 * 8);
        }
        __syncthreads();

        bf16x8 af[4], bfr[4];
        #pragma unroll
        for (int i = 0; i < 4; ++i) {
            af[i]  = *(const bf16x8*)(Alds + (wm + i * 16 + l15) * 32 + quad * 8);
            bfr[i] = *(const bf16x8*)(Blds + (wn + i * 16 + l15) * 32 + quad * 8);
        }
        #pragma unroll
        for (int i = 0; i < 4; ++i)
            #pragma unroll
            for (int j = 0; j < 4; ++j)
                acc[i][j] = __builtin_amdgcn_mfma_f32_16x16x32_bf16(
                    af[i], bfr[j], acc[i][j], 0, 0, 0);
        __syncthreads();
    }

    // Epilogue: D layout col=lane&15, row=quad*4+reg (m89/m91 verified).
    #pragma unroll
    for (int j = 0; j < 4; ++j) {
        int col = wn + j * 16 + l15;
        float bj = bias[col];
        #pragma unroll
        for (int i = 0; i < 4; ++i) {
            int rb = m0 + wm + i * 16 + quad * 4;
            #pragma unroll
            for (int r = 0; r < 4; ++r) {
                int m = rb + r;
                if (m < N_NODES)
                    __builtin_nontemporal_store(
                        fmaxf(acc[i][j][r] + bj, 0.f),
                        out + (size_t)m * D + col);
            }
        }
    }
}

extern "C" void kernel_launch(void* const* d_in, const int* in_sizes, int n_in,
                              void* d_out, int out_size, void* d_ws, size_t ws_size,
                              hipStream_t stream) {
    const float* x    = (const float*)d_in[0];
    const float* Ws   = (const float*)d_in[1];
    const float* W1   = (const float*)d_in[2];
    const float* W2   = (const float*)d_in[3];
    const float* bias = (const float*)d_in[4];
    const int* src1   = (const int*)d_in[5];
    const int* dst1   = (const int*)d_in[6];
    const int* src2   = (const int*)d_in[7];
    const int* dst2   = (const int*)d_in[8];
    float* out = (float*)d_out;

    // Workspace layout (total 180.4 MB):
    char* p = (char*)d_ws;
    unsigned short* xb  = (unsigned short*)p; p += (size_t)N_NODES * D * 2;  // 51.2 MB
    unsigned short* xa1 = (unsigned short*)p; p += (size_t)N_NODES * D * 2;  // 51.2 MB
    unsigned short* xa2 = (unsigned short*)p; p += (size_t)N_NODES * D * 2;  // 51.2 MB
    int* cnt1 = (int*)p; p += (size_t)N_NODES * 4;                           // 0.4 MB
    int* cnt2 = (int*)p; p += (size_t)N_NODES * 4;                           // 0.4 MB
    int* bkt1 = (int*)p; p += (size_t)N_NODES * CAP * 4;                     // 12.8 MB
    int* bkt2 = (int*)p; p += (size_t)N_NODES * CAP * 4;                     // 12.8 MB
    unsigned short* Wt = (unsigned short*)p;                                 // 0.39 MB

    (void)hipMemsetAsync(cnt1, 0, (size_t)2 * N_NODES * 4, stream);

    prep_kernel<<<PREP_GRID, 256, 0, stream>>>(
        x, xb, Ws, W1, W2, Wt, src1, dst1, src2, dst2, cnt1, cnt2, bkt1, bkt2);

    {   // gather-aggregate, one wave per node (both relations)
        long long total = (long long)N_NODES * 64;
        gather_kernel<<<(int)((total + 255) / 256), 256, 0, stream>>>(
            xb, cnt1, cnt2, bkt1, bkt2, xa1, xa2);
    }
    {   // MFMA GEMM + bias + relu, full-N blocks
        gemm_kernel<<<(N_NODES + 127) / 128, 512, 0, stream>>>(
            xb, xa1, xa2, Wt, bias, out);
    }
}

// Round 7
// 403.861 us; speedup vs baseline: 1.1492x; 1.1492x over previous
//
#include <hip/hip_runtime.h>

#define N_NODES 100000
#define N_EDGES 500000
#define D 256
#define CAP 32          // bucket capacity per (node, relation); λ=5 ⇒ P(deg>32)≈1e-15

typedef __bf16 bf16x8 __attribute__((ext_vector_type(8)));
typedef float  f32x4  __attribute__((ext_vector_type(4)));
typedef unsigned int u32x2 __attribute__((ext_vector_type(2)));  // nontemporal-compatible

// async global->LDS, 16B per lane; LDS dest must be wave-uniform base + lane*16
#define GLDS(gp, lp) \
    __builtin_amdgcn_global_load_lds((const __attribute__((address_space(1))) void*)(gp), \
                                     (__attribute__((address_space(3))) void*)(lp), 16, 0, 0)

// ---- bf16 helpers (manual, RNE) -------------------------------------------
__device__ __forceinline__ unsigned short f2bf(float f) {
    unsigned int u = __float_as_uint(f);
    u += 0x7fffu + ((u >> 16) & 1u);
    return (unsigned short)(u >> 16);
}
__device__ __forceinline__ float bf2f(unsigned short b) {
    return __uint_as_float(((unsigned int)b) << 16);
}

// ---------------------------------------------------------------------------
// Prep kernel, WAVE-granular role interleave. Round 4/6 showed block-range
// role ordering serializes the phases (131/152 µs at ~1.2 TB/s, VALU 1.5%).
// Per m114, heterogeneous waves co-resident on a CU overlap fully — so
// stripe roles per wave: of every 22 waves, 16 convert (streaming BW),
// 5 bucket (atomic latency), 1 W-prep. Exact: 50000 conv waves (16*3125),
// 15625 bucket waves (5*3125), 3072 pw waves (<3125).
// ---------------------------------------------------------------------------
#define PREP_BLOCKS 17188   // ceil(22*3125 waves / 4 per block)

__global__ __launch_bounds__(256) void prep_kernel(
    const float* __restrict__ x, unsigned short* __restrict__ xb,
    const float* __restrict__ Ws, const float* __restrict__ W1,
    const float* __restrict__ W2, unsigned short* __restrict__ Wt,
    const int* __restrict__ src1, const int* __restrict__ dst1,
    const int* __restrict__ src2, const int* __restrict__ dst2,
    int* __restrict__ cnt1, int* __restrict__ cnt2,
    int* __restrict__ bkt1, int* __restrict__ bkt2)
{
    const int wid  = blockIdx.x * 4 + (threadIdx.x >> 6);  // global wave id (wave-uniform)
    const int lane = threadIdx.x & 63;
    const int group = wid / 22;
    const int pos   = wid - group * 22;

    if (pos < 16) {
        // ---- convert role: x fp32 -> xb bf16, 8 elems/lane, coalesced ----
        int cw = group * 16 + pos;
        if (cw >= 50000) return;
        size_t i = (size_t)cw * 512 + (size_t)lane * 8;
        float4 a = *(const float4*)(x + i);
        float4 c = *(const float4*)(x + i + 4);
        union { unsigned short s[8]; uint4 u; } o;
        o.s[0] = f2bf(a.x); o.s[1] = f2bf(a.y); o.s[2] = f2bf(a.z); o.s[3] = f2bf(a.w);
        o.s[4] = f2bf(c.x); o.s[5] = f2bf(c.y); o.s[6] = f2bf(c.z); o.s[7] = f2bf(c.w);
        *(uint4*)(xb + i) = o.u;
    } else if (pos < 21) {
        // ---- bucket role: 1 edge/lane, cnt/bkt atomics (L2-resident) ----
        int bw = group * 5 + (pos - 16);
        int e = bw * 64 + lane;
        if (e >= 2 * N_EDGES) return;
        bool r2 = (e >= N_EDGES);
        const int* src = r2 ? src2 : src1;
        const int* dst = r2 ? dst2 : dst1;
        int* cnt = r2 ? cnt2 : cnt1;
        int* bkt = r2 ? bkt2 : bkt1;
        int ei = r2 ? e - N_EDGES : e;
        int s = src[ei], d = dst[ei];
        int p = atomicAdd(&cnt[d], 1);
        if (p < CAP) bkt[d * CAP + p] = s;
    } else {
        // ---- W-prep role: Wt[n][k] = bf16(scale_k * W[k%256][n]) ----
        int idx = group * 64 + lane;
        if (idx >= 3 * D * D) return;   // idx/64 < 3072 used; groups 3072..3124 idle
        int k = idx >> 8;
        int n = idx & (D - 1);
        const float* W = (k < D) ? Ws : (k < 2 * D ? W1 : W2);
        float scale = (k < D) ? 1.1f : 1.0f;
        Wt[(size_t)n * (3 * D) + k] = f2bf(W[(size_t)(k & (D - 1)) * D + n] * scale);
    }
}

// ---------------------------------------------------------------------------
// Gather: one wave per (node, relation) — 200K waves for max outstanding
// loads device-wide. Chunk-8 preload (8 independent 512B row-reads in
// flight), wave-uniform predicated accumulate, rare tail loop.
// xa writes NON-TEMPORAL (keep xb resident in L3).
// ---------------------------------------------------------------------------
__global__ __launch_bounds__(256) void gather_kernel(
    const unsigned short* __restrict__ xb,
    const int* __restrict__ cnt1, const int* __restrict__ cnt2,
    const int* __restrict__ bkt1, const int* __restrict__ bkt2,
    unsigned short* __restrict__ xa1, unsigned short* __restrict__ xa2)
{
    long long gid = (long long)blockIdx.x * blockDim.x + threadIdx.x;
    int w = (int)(gid >> 6);
    int lane = (int)(gid & 63);
    if (w >= 2 * N_NODES) return;
    int node = w >> 1;
    int rel  = w & 1;

    const int* cnt = rel ? cnt2 : cnt1;
    const int* bkt = rel ? bkt2 : bkt1;
    unsigned short* xa = rel ? xa2 : xa1;

    int c = cnt[node]; if (c > CAP) c = CAP;
    int sid = (lane < c) ? bkt[(size_t)node * CAP + lane] : 0;

    // 8 independent row loads in flight; dummies hit row 0 (L1-hot).
    ushort4 v[8];
    #pragma unroll
    for (int t = 0; t < 8; ++t) {
        int s = __shfl(sid, t);
        v[t] = *(const ushort4*)(xb + (size_t)s * D + lane * 4);
    }

    float a0 = 0.f, a1 = 0.f, a2 = 0.f, a3 = 0.f;
    #pragma unroll
    for (int t = 0; t < 8; ++t) {
        if (t < c) {   // wave-uniform predicate (scalar branch)
            a0 += bf2f(v[t].x); a1 += bf2f(v[t].y);
            a2 += bf2f(v[t].z); a3 += bf2f(v[t].w);
        }
    }
    // Tail (P(c>8) ≈ 6.8% at λ=5).
    for (int e = 8; e < c; ++e) {
        int s = __shfl(sid, e);
        ushort4 t = *(const ushort4*)(xb + (size_t)s * D + lane * 4);
        a0 += bf2f(t.x); a1 += bf2f(t.y); a2 += bf2f(t.z); a3 += bf2f(t.w);
    }

    u32x2 o;
    o.x = (unsigned)f2bf(a0) | ((unsigned)f2bf(a1) << 16);
    o.y = (unsigned)f2bf(a2) | ((unsigned)f2bf(a3) << 16);
    __builtin_nontemporal_store(o, (u32x2*)(xa + (size_t)node * D + lane * 4));
}

// ---------------------------------------------------------------------------
// MFMA GEMM: out = relu( [xb | xa1 | xa2] @ Wt^T + bias ), bf16 in, fp32 acc.
// M=100000, N=256 (full N per block -> A read once), K=768.
// 512 threads = 8 waves, each 64x64 (4x4 of 16x16x32 MFMA). BK=32.
// Epilogue stores non-temporal (out never re-read; keep L3 for the A-stream).
// ---------------------------------------------------------------------------
__global__ __launch_bounds__(512) void gemm_kernel(
    const unsigned short* __restrict__ xb,
    const unsigned short* __restrict__ xa1,
    const unsigned short* __restrict__ xa2,
    const unsigned short* __restrict__ Wt,   // [256 n][768 k] bf16, pre-scaled
    const float* __restrict__ bias, float* __restrict__ out)
{
    __shared__ unsigned short Alds[128 * 32];   // [row][k] k-contiguous, 8 KB
    __shared__ unsigned short Blds[256 * 32];   // [n][k]  k-contiguous, 16 KB

    const int tid  = threadIdx.x;
    const int lane = tid & 63;
    const int wave = tid >> 6;          // 0..7
    const int quad = lane >> 4;
    const int l15  = lane & 15;
    const int m0 = blockIdx.x * 128;
    const int wm = (wave >> 2) * 64;    // 2 m-tiles x 4 n-tiles of 64
    const int wn = (wave & 3) * 64;

    const unsigned short* Aseg[3] = {xb, xa1, xa2};

    f32x4 acc[4][4] = {};

    for (int kt = 0; kt < 24; ++kt) {
        const int seg = kt >> 3;
        const int ko  = (kt & 7) * 32;
        const unsigned short* __restrict__ A = Aseg[seg];

        // A tile: 512 slots of 16B, 1/thread.
        {
            int row = tid >> 2, kq = tid & 3;
            int m = m0 + row;
            if (m >= N_NODES) m = N_NODES - 1;   // junk rows discarded in epilogue
            GLDS(A + (size_t)m * D + ko + kq * 8, Alds + tid * 8);
        }
        // B tile: 1024 slots of 16B, 2/thread (Wt rows are L2-resident).
        {
            int n = tid >> 2, kq = tid & 3;
            GLDS(Wt + (size_t)n * (3 * D) + kt * 32 + kq * 8, Blds + tid * 8);
        }
        {
            int t2 = tid + 512;
            int n = t2 >> 2, kq = t2 & 3;
            GLDS(Wt + (size_t)n * (3 * D) + kt * 32 + kq * 8, Blds + t2 * 8);
        }
        __syncthreads();

        bf16x8 af[4], bfr[4];
        #pragma unroll
        for (int i = 0; i < 4; ++i) {
            af[i]  = *(const bf16x8*)(Alds + (wm + i * 16 + l15) * 32 + quad * 8);
            bfr[i] = *(const bf16x8*)(Blds + (wn + i * 16 + l15) * 32 + quad * 8);
        }
        #pragma unroll
        for (int i = 0; i < 4; ++i)
            #pragma unroll
            for (int j = 0; j < 4; ++j)
                acc[i][j] = __builtin_amdgcn_mfma_f32_16x16x32_bf16(
                    af[i], bfr[j], acc[i][j], 0, 0, 0);
        __syncthreads();
    }

    // Epilogue: D layout col=lane&15, row=quad*4+reg (m89/m91 verified).
    #pragma unroll
    for (int j = 0; j < 4; ++j) {
        int col = wn + j * 16 + l15;
        float bj = bias[col];
        #pragma unroll
        for (int i = 0; i < 4; ++i) {
            int rb = m0 + wm + i * 16 + quad * 4;
            #pragma unroll
            for (int r = 0; r < 4; ++r) {
                int m = rb + r;
                if (m < N_NODES)
                    __builtin_nontemporal_store(
                        fmaxf(acc[i][j][r] + bj, 0.f),
                        out + (size_t)m * D + col);
            }
        }
    }
}

extern "C" void kernel_launch(void* const* d_in, const int* in_sizes, int n_in,
                              void* d_out, int out_size, void* d_ws, size_t ws_size,
                              hipStream_t stream) {
    const float* x    = (const float*)d_in[0];
    const float* Ws   = (const float*)d_in[1];
    const float* W1   = (const float*)d_in[2];
    const float* W2   = (const float*)d_in[3];
    const float* bias = (const float*)d_in[4];
    const int* src1   = (const int*)d_in[5];
    const int* dst1   = (const int*)d_in[6];
    const int* src2   = (const int*)d_in[7];
    const int* dst2   = (const int*)d_in[8];
    float* out = (float*)d_out;

    // Workspace layout (total 180.4 MB):
    char* p = (char*)d_ws;
    unsigned short* xb  = (unsigned short*)p; p += (size_t)N_NODES * D * 2;  // 51.2 MB
    unsigned short* xa1 = (unsigned short*)p; p += (size_t)N_NODES * D * 2;  // 51.2 MB
    unsigned short* xa2 = (unsigned short*)p; p += (size_t)N_NODES * D * 2;  // 51.2 MB
    int* cnt1 = (int*)p; p += (size_t)N_NODES * 4;                           // 0.4 MB
    int* cnt2 = (int*)p; p += (size_t)N_NODES * 4;                           // 0.4 MB
    int* bkt1 = (int*)p; p += (size_t)N_NODES * CAP * 4;                     // 12.8 MB
    int* bkt2 = (int*)p; p += (size_t)N_NODES * CAP * 4;                     // 12.8 MB
    unsigned short* Wt = (unsigned short*)p;                                 // 0.39 MB

    (void)hipMemsetAsync(cnt1, 0, (size_t)2 * N_NODES * 4, stream);

    prep_kernel<<<PREP_BLOCKS, 256, 0, stream>>>(
        x, xb, Ws, W1, W2, Wt, src1, dst1, src2, dst2, cnt1, cnt2, bkt1, bkt2);

    {   // gather-aggregate, one wave per (node, relation)
        long long total = (long long)2 * N_NODES * 64;
        gather_kernel<<<(int)((total + 255) / 256), 256, 0, stream>>>(
            xb, cnt1, cnt2, bkt1, bkt2, xa1, xa2);
    }
    {   // MFMA GEMM + bias + relu, full-N blocks
        gemm_kernel<<<(N_NODES + 127) / 128, 512, 0, stream>>>(
            xb, xa1, xa2, Wt, bias, out);
    }
}

// Round 8
// 403.109 us; speedup vs baseline: 1.1513x; 1.0019x over previous
//
#include <hip/hip_runtime.h>

#define N_NODES 100000
#define N_EDGES 500000
#define D 256
#define CAP 32          // bucket capacity per (node, relation); λ=5 ⇒ P(deg>32)≈1e-15

typedef __bf16 bf16x8 __attribute__((ext_vector_type(8)));
typedef float  f32x4  __attribute__((ext_vector_type(4)));
typedef unsigned int u32x2 __attribute__((ext_vector_type(2)));  // nontemporal-compatible

// ---- bf16 helpers (manual, RNE) -------------------------------------------
__device__ __forceinline__ unsigned short f2bf(float f) {
    unsigned int u = __float_as_uint(f);
    u += 0x7fffu + ((u >> 16) & 1u);
    return (unsigned short)(u >> 16);
}
__device__ __forceinline__ float bf2f(unsigned short b) {
    return __uint_as_float(((unsigned int)b) << 16);
}

// ---------------------------------------------------------------------------
// Prep kernel, WAVE-granular role interleave (round-7 win: heterogeneous
// waves co-resident per m114 overlap; block-range ordering serialized).
// Of every 22 waves: 16 convert, 5 bucket, 1 W-prep.
// ---------------------------------------------------------------------------
#define PREP_BLOCKS 17188   // ceil(22*3125 waves / 4 per block)

__global__ __launch_bounds__(256) void prep_kernel(
    const float* __restrict__ x, unsigned short* __restrict__ xb,
    const float* __restrict__ Ws, const float* __restrict__ W1,
    const float* __restrict__ W2, unsigned short* __restrict__ Wt,
    const int* __restrict__ src1, const int* __restrict__ dst1,
    const int* __restrict__ src2, const int* __restrict__ dst2,
    int* __restrict__ cnt1, int* __restrict__ cnt2,
    int* __restrict__ bkt1, int* __restrict__ bkt2)
{
    const int wid  = blockIdx.x * 4 + (threadIdx.x >> 6);  // global wave id
    const int lane = threadIdx.x & 63;
    const int group = wid / 22;
    const int pos   = wid - group * 22;

    if (pos < 16) {
        // ---- convert role: x fp32 -> xb bf16, 8 elems/lane, coalesced ----
        int cw = group * 16 + pos;
        if (cw >= 50000) return;
        size_t i = (size_t)cw * 512 + (size_t)lane * 8;
        float4 a = *(const float4*)(x + i);
        float4 c = *(const float4*)(x + i + 4);
        union { unsigned short s[8]; uint4 u; } o;
        o.s[0] = f2bf(a.x); o.s[1] = f2bf(a.y); o.s[2] = f2bf(a.z); o.s[3] = f2bf(a.w);
        o.s[4] = f2bf(c.x); o.s[5] = f2bf(c.y); o.s[6] = f2bf(c.z); o.s[7] = f2bf(c.w);
        *(uint4*)(xb + i) = o.u;
    } else if (pos < 21) {
        // ---- bucket role: 1 edge/lane, cnt/bkt atomics (L2-resident) ----
        int bw = group * 5 + (pos - 16);
        int e = bw * 64 + lane;
        if (e >= 2 * N_EDGES) return;
        bool r2 = (e >= N_EDGES);
        const int* src = r2 ? src2 : src1;
        const int* dst = r2 ? dst2 : dst1;
        int* cnt = r2 ? cnt2 : cnt1;
        int* bkt = r2 ? bkt2 : bkt1;
        int ei = r2 ? e - N_EDGES : e;
        int s = src[ei], d = dst[ei];
        int p = atomicAdd(&cnt[d], 1);
        if (p < CAP) bkt[d * CAP + p] = s;
    } else {
        // ---- W-prep role: Wt[n][k] = bf16(scale_k * W[k%256][n]) ----
        int idx = group * 64 + lane;
        if (idx >= 3 * D * D) return;
        int k = idx >> 8;
        int n = idx & (D - 1);
        const float* W = (k < D) ? Ws : (k < 2 * D ? W1 : W2);
        float scale = (k < D) ? 1.1f : 1.0f;
        Wt[(size_t)n * (3 * D) + k] = f2bf(W[(size_t)(k & (D - 1)) * D + n] * scale);
    }
}

// ---------------------------------------------------------------------------
// Gather: one wave per (node, relation). Chunk-8 preload (8 independent 512B
// row-reads in flight), wave-uniform predicated accumulate, rare tail loop.
// xa writes NON-TEMPORAL (keep xb resident in L3).
// ---------------------------------------------------------------------------
__global__ __launch_bounds__(256) void gather_kernel(
    const unsigned short* __restrict__ xb,
    const int* __restrict__ cnt1, const int* __restrict__ cnt2,
    const int* __restrict__ bkt1, const int* __restrict__ bkt2,
    unsigned short* __restrict__ xa1, unsigned short* __restrict__ xa2)
{
    long long gid = (long long)blockIdx.x * blockDim.x + threadIdx.x;
    int w = (int)(gid >> 6);
    int lane = (int)(gid & 63);
    if (w >= 2 * N_NODES) return;
    int node = w >> 1;
    int rel  = w & 1;

    const int* cnt = rel ? cnt2 : cnt1;
    const int* bkt = rel ? bkt2 : bkt1;
    unsigned short* xa = rel ? xa2 : xa1;

    int c = cnt[node]; if (c > CAP) c = CAP;
    int sid = (lane < c) ? bkt[(size_t)node * CAP + lane] : 0;

    ushort4 v[8];
    #pragma unroll
    for (int t = 0; t < 8; ++t) {
        int s = __shfl(sid, t);
        v[t] = *(const ushort4*)(xb + (size_t)s * D + lane * 4);
    }

    float a0 = 0.f, a1 = 0.f, a2 = 0.f, a3 = 0.f;
    #pragma unroll
    for (int t = 0; t < 8; ++t) {
        if (t < c) {   // wave-uniform predicate (scalar branch)
            a0 += bf2f(v[t].x); a1 += bf2f(v[t].y);
            a2 += bf2f(v[t].z); a3 += bf2f(v[t].w);
        }
    }
    for (int e = 8; e < c; ++e) {
        int s = __shfl(sid, e);
        ushort4 t = *(const ushort4*)(xb + (size_t)s * D + lane * 4);
        a0 += bf2f(t.x); a1 += bf2f(t.y); a2 += bf2f(t.z); a3 += bf2f(t.w);
    }

    u32x2 o;
    o.x = (unsigned)f2bf(a0) | ((unsigned)f2bf(a1) << 16);
    o.y = (unsigned)f2bf(a2) | ((unsigned)f2bf(a3) << 16);
    __builtin_nontemporal_store(o, (u32x2*)(xa + (size_t)node * D + lane * 4));
}

// ---------------------------------------------------------------------------
// MFMA GEMM: out = relu( [xb | xa1 | xa2] @ Wt^T + bias ), bf16 in, fp32 acc.
// M=100000, N=256 (full N per block -> A read once), K=768. 512 thr, 8 waves
// of 64x64 (4x4 of 16x16x32 MFMA), BK=32.
// Round-8 change: register-routed staging with XOR-SWIZZLED ds_write_b128
// (chunk c -> c ^ ((row>>1)&3)). Round-7 GLDS layout gave 8-way ds_read
// conflicts (4.8M, MfmaUtil 14%): 16 rows @ stride 64B = 2 banks/phase.
// Swizzle spreads each 16-lane phase over 8 bank-groups = 2-way = free.
// Register staging also enables SW pipelining: kt+1 global loads issue
// before kt's MFMA; vmcnt drains at kt+1's ds_write, not a barrier.
// ---------------------------------------------------------------------------
__global__ __launch_bounds__(512) void gemm_kernel(
    const unsigned short* __restrict__ xb,
    const unsigned short* __restrict__ xa1,
    const unsigned short* __restrict__ xa2,
    const unsigned short* __restrict__ Wt,   // [256 n][768 k] bf16, pre-scaled
    const float* __restrict__ bias, float* __restrict__ out)
{
    __shared__ unsigned short Alds[128 * 32];   // [row][swizzled k-chunk] 8 KB
    __shared__ unsigned short Blds[256 * 32];   // [n][swizzled k-chunk] 16 KB

    const int tid  = threadIdx.x;
    const int lane = tid & 63;
    const int wave = tid >> 6;          // 0..7
    const int quad = lane >> 4;
    const int l15  = lane & 15;
    const int m0 = blockIdx.x * 128;
    const int wm = (wave >> 2) * 64;    // 2 m-tiles x 4 n-tiles of 64
    const int wn = (wave & 3) * 64;

    const unsigned short* Aseg[3] = {xb, xa1, xa2};

    // Staging geometry: thread -> (row, 16B chunk kq). A: 512 slots (128x4).
    // B: 1024 slots (256x4), 2 per thread. Swizzled LDS offsets (shorts).
    const int rowA = tid >> 2, kqA = tid & 3;
    int mA = m0 + rowA; if (mA >= N_NODES) mA = N_NODES - 1;
    const int wAoff  = rowA * 32 + ((kqA ^ ((rowA >> 1) & 3)) * 8);
    const int nB0 = tid >> 2, nB1 = nB0 + 128;
    const int wB0off = nB0 * 32 + ((kqA ^ ((nB0 >> 1) & 3)) * 8);
    const int wB1off = nB1 * 32 + ((kqA ^ ((nB1 >> 1) & 3)) * 8);
    const int swz = (l15 >> 1) & 3;     // read-side chunk swizzle (row>>1)&3

    f32x4 acc[4][4] = {};

    // Prefetch kt=0.
    uint4 ra  = *(const uint4*)(Aseg[0] + (size_t)mA * D + kqA * 8);
    uint4 rb0 = *(const uint4*)(Wt + (size_t)nB0 * (3 * D) + kqA * 8);
    uint4 rb1 = *(const uint4*)(Wt + (size_t)nB1 * (3 * D) + kqA * 8);

    for (int kt = 0; kt < 24; ++kt) {
        *(uint4*)(Alds + wAoff) = ra;
        *(uint4*)(Blds + wB0off) = rb0;
        *(uint4*)(Blds + wB1off) = rb1;
        __syncthreads();

        if (kt + 1 < 24) {   // issue next tile's global loads before MFMA
            const unsigned short* __restrict__ An = Aseg[(kt + 1) >> 3];
            const int kon = ((kt + 1) & 7) * 32;
            ra  = *(const uint4*)(An + (size_t)mA * D + kon + kqA * 8);
            rb0 = *(const uint4*)(Wt + (size_t)nB0 * (3 * D) + (kt + 1) * 32 + kqA * 8);
            rb1 = *(const uint4*)(Wt + (size_t)nB1 * (3 * D) + (kt + 1) * 32 + kqA * 8);
        }

        bf16x8 af[4], bfr[4];
        #pragma unroll
        for (int i = 0; i < 4; ++i) {
            af[i]  = *(const bf16x8*)(Alds + (wm + i * 16 + l15) * 32 + ((quad ^ swz) * 8));
            bfr[i] = *(const bf16x8*)(Blds + (wn + i * 16 + l15) * 32 + ((quad ^ swz) * 8));
        }
        #pragma unroll
        for (int i = 0; i < 4; ++i)
            #pragma unroll
            for (int j = 0; j < 4; ++j)
                acc[i][j] = __builtin_amdgcn_mfma_f32_16x16x32_bf16(
                    af[i], bfr[j], acc[i][j], 0, 0, 0);
        __syncthreads();
    }

    // Epilogue: D layout col=lane&15, row=quad*4+reg (m89/m91 verified).
    #pragma unroll
    for (int j = 0; j < 4; ++j) {
        int col = wn + j * 16 + l15;
        float bj = bias[col];
        #pragma unroll
        for (int i = 0; i < 4; ++i) {
            int rb = m0 + wm + i * 16 + quad * 4;
            #pragma unroll
            for (int r = 0; r < 4; ++r) {
                int m = rb + r;
                if (m < N_NODES)
                    __builtin_nontemporal_store(
                        fmaxf(acc[i][j][r] + bj, 0.f),
                        out + (size_t)m * D + col);
            }
        }
    }
}

extern "C" void kernel_launch(void* const* d_in, const int* in_sizes, int n_in,
                              void* d_out, int out_size, void* d_ws, size_t ws_size,
                              hipStream_t stream) {
    const float* x    = (const float*)d_in[0];
    const float* Ws   = (const float*)d_in[1];
    const float* W1   = (const float*)d_in[2];
    const float* W2   = (const float*)d_in[3];
    const float* bias = (const float*)d_in[4];
    const int* src1   = (const int*)d_in[5];
    const int* dst1   = (const int*)d_in[6];
    const int* src2   = (const int*)d_in[7];
    const int* dst2   = (const int*)d_in[8];
    float* out = (float*)d_out;

    // Workspace layout (total 180.4 MB):
    char* p = (char*)d_ws;
    unsigned short* xb  = (unsigned short*)p; p += (size_t)N_NODES * D * 2;  // 51.2 MB
    unsigned short* xa1 = (unsigned short*)p; p += (size_t)N_NODES * D * 2;  // 51.2 MB
    unsigned short* xa2 = (unsigned short*)p; p += (size_t)N_NODES * D * 2;  // 51.2 MB
    int* cnt1 = (int*)p; p += (size_t)N_NODES * 4;                           // 0.4 MB
    int* cnt2 = (int*)p; p += (size_t)N_NODES * 4;                           // 0.4 MB
    int* bkt1 = (int*)p; p += (size_t)N_NODES * CAP * 4;                     // 12.8 MB
    int* bkt2 = (int*)p; p += (size_t)N_NODES * CAP * 4;                     // 12.8 MB
    unsigned short* Wt = (unsigned short*)p;                                 // 0.39 MB

    (void)hipMemsetAsync(cnt1, 0, (size_t)2 * N_NODES * 4, stream);

    prep_kernel<<<PREP_BLOCKS, 256, 0, stream>>>(
        x, xb, Ws, W1, W2, Wt, src1, dst1, src2, dst2, cnt1, cnt2, bkt1, bkt2);

    {   // gather-aggregate, one wave per (node, relation)
        long long total = (long long)2 * N_NODES * 64;
        gather_kernel<<<(int)((total + 255) / 256), 256, 0, stream>>>(
            xb, cnt1, cnt2, bkt1, bkt2, xa1, xa2);
    }
    {   // MFMA GEMM + bias + relu, full-N blocks
        gemm_kernel<<<(N_NODES + 127) / 128, 512, 0, stream>>>(
            xb, xa1, xa2, Wt, bias, out);
    }
}